// Round 4
// baseline (3790.883 us; speedup 1.0000x reference)
//
#include <hip/hip_runtime.h>
#include <cstdint>

// ---------------- problem constants ----------------
#define NYD   256
#define NXD   256
#define PADC  22            // PML + FD_PAD
#define NYP_  300           // NY + 2*PAD
#define NXP_  300
#define NTT   250
#define NSHOT_ 2
#define NSRC_  8
#define NREC_  64
#define DT_   0.0005f

// fused-path geometry (tile B=32, guarded global arrays)
#define BT    32            // output tile edge
#define NTILE 10            // ceil(300/32)
#define GG    40            // global guard ring (covers stage halo 16 + edge-tile overhang 20+16)
#define STG   380           // NXP_ + 2*GG
#define FG    (STG*STG)     // per-shot field size (words)
// legacy-path geometry (round-0 proven kernel)
#define LGD   4
#define LST   308

// ---------------- zero workspace ----------------
__global__ void zero_kernel(float* __restrict__ p, long n) {
    long i = (long)blockIdx.x * blockDim.x + threadIdx.x;
    long stride = (long)gridDim.x * blockDim.x;
    for (; i < n; i += stride) p[i] = 0.0f;
}

// ---------------- fused-path setup: v2dt2, PML profiles, receiver tile bins ----------------
__global__ void populateT_kernel(const float* __restrict__ v,
                                 const int* __restrict__ recloc,
                                 float* __restrict__ v2dt2,   // [FG], guard stays 0
                                 float* __restrict__ prof,    // [2*STG]: a, b (guard 0)
                                 unsigned long long* __restrict__ recbin) { // [NSHOT][NTILE*NTILE]
    int i = blockIdx.x * 256 + threadIdx.x;

    if (i < NYP_ * NXP_) {
        int y = i / NXP_, x = i % NXP_;
        int vy = min(max(y - PADC, 0), NYD - 1);
        int vx = min(max(x - PADC, 0), NXD - 1);
        float vv = v[vy * NXD + vx];
        v2dt2[(y + GG) * STG + (x + GG)] = vv * vv * (DT_ * DT_);
    }

    if (i < NYP_) {  // DY == DX and NYP == NXP: one profile pair serves both axes
        float fi = (float)i;
        float d = fmaxf(22.0f - fi, fi - 277.0f);
        float frac = fminf(fmaxf(d * (1.0f / 20.0f), 0.0f), 1.0f);
        float sigma_max = 3.0f * 4000.0f * logf(1000.0f) / (2.0f * 20.0f * 5.0f);
        float sigma = sigma_max * frac * frac;
        float alpha = 3.14159265358979323846f * 25.0f * (1.0f - frac);
        float b = expf(-(sigma + alpha) * DT_);
        float a = sigma / (sigma + alpha + 1e-9f) * (b - 1.0f);
        prof[GG + i] = a;
        prof[STG + GG + i] = b;
    }

    if (i < NSHOT_ * NREC_) {
        int ry = recloc[2 * i] + PADC;      // [22,278)
        int rx = recloc[2 * i + 1] + PADC;
        int shot = i / NREC_;
        int r = i % NREC_;
        int tile = (ry / BT) * NTILE + (rx / BT);
        atomicOr(&recbin[shot * (NTILE * NTILE) + tile], 1ull << r);
    }
}

// ---------------- fused kernel: T time steps per launch ----------------
// Per 32x32 output tile: stage wf(t) with halo 4T in LDS; per step k=1..T:
//  [psi phase] in-place psi update on region P_k (psi is self-cell + wf-stencil)
//  [wf phase]  wf(t+k)+zeta on shrinking region W_k (halo 4(T-k)); zeta, wfm,
//              v2dt2 and per-cell source masks live in REGISTERS (static NC
//              unroll). wf ping-pongs between 2 LDS buffers.
// Regions: W_k = tile + 4(T-k) halo; psi-y needs y-halo 4(T-k)+2. Guarded
// global arrays with v2=0 & prof=0 outside the domain make wf/psi/zeta stay
// exactly 0 there (Dirichlet), so fringe cells never pollute valid ones.
template <int T>
__global__ __launch_bounds__(256) void fusedT_kernel(
    const float* __restrict__ wfm_all,  // wf(t-1)
    const float* __restrict__ wfc_all,  // wf(t)
    float* __restrict__ wAo_all,        // out: wf(t+T-1)
    float* __restrict__ wBo_all,        // out: wf(t+T)
    const float* __restrict__ pyR_all, float* __restrict__ pyW_all,
    const float* __restrict__ pxR_all, float* __restrict__ pxW_all,
    const float* __restrict__ zyR_all, float* __restrict__ zyW_all,
    const float* __restrict__ zxR_all, float* __restrict__ zxW_all,
    const float* __restrict__ v2g, const float* __restrict__ profg,
    const unsigned long long* __restrict__ recbin,
    const int* __restrict__ srcloc, const int* __restrict__ recloc,
    const float* __restrict__ amps,   // [NSHOT][NSRC][NT]
    float* __restrict__ out,          // [NSHOT][NREC][NT]
    int t) {
    constexpr int H    = 4 * T;           // stage halo
    constexpr int SW   = BT + 2 * H;      // stage width
    constexpr int PYH  = 4 * (T - 1) + 2; // psi-y array y-halo
    constexpr int PXH  = 4 * (T - 1);     // psi-y array x-halo == W_1 halo
    constexpr int PH_Y = BT + 2 * PYH, PW_Y = BT + 2 * PXH;  // psiy dims
    constexpr int PH_X = BT + 2 * PXH, PW_X = BT + 2 * PYH;  // psix dims
    constexpr int WW   = BT + 2 * PXH;    // W_1 width
    constexpr int NC   = (WW * WW + 255) / 256;  // owned cells per thread

    __shared__ float swf[2][SW][SW + 1];
    __shared__ float spy[PH_Y][PW_Y + 1];
    __shared__ float spx[PH_X][PW_X + 1];
    __shared__ float sprof[4][SW];        // ay, by, ax, bx by stage index
    __shared__ int   ssy[NSRC_], ssx[NSRC_];
    __shared__ int   sry[NREC_], srx[NREC_];
    __shared__ unsigned long long srb;

    const int tid  = threadIdx.x;
    const int shot = blockIdx.z;
    const int by0  = blockIdx.y * BT;
    const int bx0  = blockIdx.x * BT;

    const float* wfmg = wfm_all + shot * FG;
    const float* wfcg = wfc_all + shot * FG;
    float*       wAo  = wAo_all + shot * FG;
    float*       wBo  = wBo_all + shot * FG;
    const float* pyR  = pyR_all + shot * FG;
    float*       pyW  = pyW_all + shot * FG;
    const float* pxR  = pxR_all + shot * FG;
    float*       pxW  = pxW_all + shot * FG;
    const float* zyR  = zyR_all + shot * FG;
    float*       zyW  = zyW_all + shot * FG;
    const float* zxR  = zxR_all + shot * FG;
    float*       zxW  = zxW_all + shot * FG;

    const float ih  = 0.2f;    // 1/DY
    const float ih2 = 0.04f;   // 1/DY^2
    const float C1A = 2.0f / 3.0f, C1B = 1.0f / 12.0f;
    const float C2A = 4.0f / 3.0f, C2B = -1.0f / 12.0f, C2C = -2.5f;

    // ---- stage wf(t) ----
#pragma unroll
    for (int li = 0; li < (SW * SW + 255) / 256; li++) {
        int lin = tid + li * 256;
        if (lin < SW * SW) {
            int r = lin / SW, c = lin % SW;
            swf[0][r][c] = wfcg[(by0 + r - H + GG) * STG + (bx0 + c - H + GG)];
        }
    }
    // ---- stage psi(t) ----
#pragma unroll
    for (int li = 0; li < (PH_Y * PW_Y + 255) / 256; li++) {
        int lin = tid + li * 256;
        if (lin < PH_Y * PW_Y) {
            int r = lin / PW_Y, c = lin % PW_Y;
            spy[r][c] = pyR[(by0 + r - PYH + GG) * STG + (bx0 + c - PXH + GG)];
        }
    }
#pragma unroll
    for (int li = 0; li < (PH_X * PW_X + 255) / 256; li++) {
        int lin = tid + li * 256;
        if (lin < PH_X * PW_X) {
            int r = lin / PW_X, c = lin % PW_X;
            spx[r][c] = pxR[(by0 + r - PXH + GG) * STG + (bx0 + c - PYH + GG)];
        }
    }
    // ---- stage prof slices, src/rec lists ----
    if (tid < SW) {
        int gy = by0 + tid - H, gx = bx0 + tid - H;
        sprof[0][tid] = profg[GG + gy];
        sprof[1][tid] = profg[STG + GG + gy];
        sprof[2][tid] = profg[GG + gx];
        sprof[3][tid] = profg[STG + GG + gx];
    }
    if (tid < NSRC_) {
        ssy[tid] = srcloc[(shot * NSRC_ + tid) * 2]     + PADC - by0;
        ssx[tid] = srcloc[(shot * NSRC_ + tid) * 2 + 1] + PADC - bx0;
    }
    if (tid < NREC_) {
        sry[tid] = recloc[(shot * NREC_ + tid) * 2]     + PADC - by0;
        srx[tid] = recloc[(shot * NREC_ + tid) * 2 + 1] + PADC - bx0;
    }
    if (tid == 0) srb = recbin[shot * (NTILE * NTILE) + blockIdx.y * NTILE + blockIdx.x];
    __syncthreads();

    // ---- owned-cell register state (W_1 enumeration) ----
    float zy[NC], zx[NC], wm[NC], vdv[NC];
    unsigned msk[NC];
#pragma unroll
    for (int i = 0; i < NC; i++) {
        int lin = tid + i * 256;
        zy[i] = 0.f; zx[i] = 0.f; wm[i] = 0.f; vdv[i] = 0.f; msk[i] = 0u;
        if (lin < WW * WW) {
            int y = lin / WW - PXH, x = lin % WW - PXH;
            int g = (by0 + y + GG) * STG + (bx0 + x + GG);
            zy[i]  = zyR[g];
            zx[i]  = zxR[g];
            wm[i]  = wfmg[g];
            vdv[i] = v2g[g];
#pragma unroll
            for (int q = 0; q < NSRC_; q++)
                if (ssy[q] == y && ssx[q] == x) msk[i] |= 1u << q;
        }
    }

    // ---- T fused steps ----
    int cur = 0;
#pragma unroll
    for (int k = 1; k <= T; k++) {
        const int hw = 4 * (T - k);     // wf-region halo this step (compile-time)
        const int hp = hw + 2;          // psi y-halo this step

        // psi-y phase (in place; reads own cell + wf stencil only)
#pragma unroll
        for (int li = 0; li < (PH_Y * PW_Y + 255) / 256; li++) {
            int lin = tid + li * 256;
            if (lin < PH_Y * PW_Y) {
                int y = lin / PW_Y - PYH, x = lin % PW_Y - PXH;
                if (y >= -hp && y < BT + hp && x >= -hw && x < BT + hw) {
                    float dw = (C1A * (swf[cur][y + 1 + H][x + H] - swf[cur][y - 1 + H][x + H])
                              - C1B * (swf[cur][y + 2 + H][x + H] - swf[cur][y - 2 + H][x + H])) * ih;
                    spy[y + PYH][x + PXH] = sprof[1][y + H] * spy[y + PYH][x + PXH]
                                          + sprof[0][y + H] * dw;
                }
            }
        }
        // psi-x phase
#pragma unroll
        for (int li = 0; li < (PH_X * PW_X + 255) / 256; li++) {
            int lin = tid + li * 256;
            if (lin < PH_X * PW_X) {
                int y = lin / PW_X - PXH, x = lin % PW_X - PYH;
                if (y >= -hw && y < BT + hw && x >= -hp && x < BT + hp) {
                    float dw = (C1A * (swf[cur][y + H][x + 1 + H] - swf[cur][y + H][x - 1 + H])
                              - C1B * (swf[cur][y + H][x + 2 + H] - swf[cur][y + H][x - 2 + H])) * ih;
                    spx[y + PXH][x + PYH] = sprof[3][x + H] * spx[y + PXH][x + PYH]
                                          + sprof[2][x + H] * dw;
                }
            }
        }
        __syncthreads();

        // wf + zeta phase (owned cells; zeta/wfm/v2/src in registers)
#pragma unroll
        for (int i = 0; i < NC; i++) {
            int lin = tid + i * 256;
            if (lin < WW * WW) {
                int y = lin / WW - PXH, x = lin % WW - PXH;
                if (y >= -hw && y < BT + hw && x >= -hw && x < BT + hw) {
                    float wc = swf[cur][y + H][x + H];
                    float d2y = (C2B * (swf[cur][y - 2 + H][x + H] + swf[cur][y + 2 + H][x + H])
                               + C2A * (swf[cur][y - 1 + H][x + H] + swf[cur][y + 1 + H][x + H])
                               + C2C * wc) * ih2;
                    float d2x = (C2B * (swf[cur][y + H][x - 2 + H] + swf[cur][y + H][x + 2 + H])
                               + C2A * (swf[cur][y + H][x - 1 + H] + swf[cur][y + H][x + 1 + H])
                               + C2C * wc) * ih2;
                    float dpy = (C1A * (spy[y + 1 + PYH][x + PXH] - spy[y - 1 + PYH][x + PXH])
                               - C1B * (spy[y + 2 + PYH][x + PXH] - spy[y - 2 + PYH][x + PXH])) * ih;
                    float dpx = (C1A * (spx[y + PXH][x + 1 + PYH] - spx[y + PXH][x - 1 + PYH])
                               - C1B * (spx[y + PXH][x + 2 + PYH] - spx[y + PXH][x - 2 + PYH])) * ih;
                    float ay = sprof[0][y + H], by = sprof[1][y + H];
                    float ax = sprof[2][x + H], bx = sprof[3][x + H];
                    zy[i] = by * zy[i] + ay * (d2y + dpy);
                    zx[i] = bx * zx[i] + ax * (d2x + dpx);
                    float wnew = 2.0f * wc - wm[i]
                               + vdv[i] * (d2y + d2x + dpy + dpx + zy[i] + zx[i]);
                    if (msk[i]) {
#pragma unroll
                        for (int q = 0; q < NSRC_; q++)
                            if (msk[i] & (1u << q))
                                wnew += vdv[i] * amps[(shot * NSRC_ + q) * NTT + t + k - 1];
                    }
                    wm[i] = wc;
                    swf[cur ^ 1][y + H][x + H] = wnew;
                }
            }
        }
        __syncthreads();

        // record receivers owned by this tile (read-only; safe alongside next psi phase)
        if (tid < NREC_ && ((srb >> tid) & 1ull))
            out[(shot * NREC_ + tid) * NTT + t + k - 1] = swf[cur ^ 1][sry[tid] + H][srx[tid] + H];

        cur ^= 1;
    }

    // ---- write back output tile: wf(t+T), wf(t+T-1), psi(t+T), zeta(t+T) ----
#pragma unroll
    for (int i = 0; i < NC; i++) {
        int lin = tid + i * 256;
        if (lin < WW * WW) {
            int y = lin / WW - PXH, x = lin % WW - PXH;
            if (y >= 0 && y < BT && x >= 0 && x < BT) {
                int gy = by0 + y, gx = bx0 + x;
                if (gy < NYP_ && gx < NXP_) {
                    int g = (gy + GG) * STG + (gx + GG);
                    wBo[g] = swf[cur][y + H][x + H];
                    wAo[g] = wm[i];
                    pyW[g] = spy[y + PYH][x + PXH];
                    pxW[g] = spx[y + PXH][x + PYH];
                    zyW[g] = zy[i];
                    zxW[g] = zx[i];
                }
            }
        }
    }
}

// ================= legacy path (round-0 proven kernel, ws-size fallback) =================
__global__ void populateL_kernel(const float* __restrict__ v,
                                 const int* __restrict__ srcloc,
                                 const int* __restrict__ recloc,
                                 float* __restrict__ v2dt2,
                                 float* __restrict__ prof,
                                 unsigned* __restrict__ srcmask,
                                 unsigned long long* __restrict__ recmask) {
    const long f = (long)LST * LST;
    int i = blockIdx.x * 256 + threadIdx.x;
    if (i < NYP_ * NXP_) {
        int y = i / NXP_, x = i % NXP_;
        int vy = min(max(y - PADC, 0), NYD - 1);
        int vx = min(max(x - PADC, 0), NXD - 1);
        float vv = v[vy * NXD + vx];
        v2dt2[(y + LGD) * LST + (x + LGD)] = vv * vv * (DT_ * DT_);
    }
    if (i < NYP_) {
        float fi = (float)i;
        float d = fmaxf(22.0f - fi, fi - 277.0f);
        float frac = fminf(fmaxf(d * (1.0f / 20.0f), 0.0f), 1.0f);
        float sigma_max = 3.0f * 4000.0f * logf(1000.0f) / (2.0f * 20.0f * 5.0f);
        float sigma = sigma_max * frac * frac;
        float alpha = 3.14159265358979323846f * 25.0f * (1.0f - frac);
        float b = expf(-(sigma + alpha) * DT_);
        float a = sigma / (sigma + alpha + 1e-9f) * (b - 1.0f);
        prof[LGD + i] = a;
        prof[LST + LGD + i] = b;
    }
    if (i < NSHOT_ * NSRC_) {
        int sy = srcloc[2 * i] + PADC;
        int sx = srcloc[2 * i + 1] + PADC;
        atomicOr(&srcmask[(i / NSRC_) * f + (long)(sy + LGD) * LST + (sx + LGD)], 1u << (i % NSRC_));
    }
    if (i >= 1024 && i < 1024 + NSHOT_ * NREC_) {
        int j = i - 1024;
        int ry = recloc[2 * j] + PADC;
        int rx = recloc[2 * j + 1] + PADC;
        atomicOr(&recmask[(j / NREC_) * f + (long)(ry + LGD) * LST + (rx + LGD)], 1ull << (j % NREC_));
    }
}

__global__ __launch_bounds__(256) void stepL_kernel(
    const float* __restrict__ wfc_all,  float* __restrict__ wfn_all,
    const float* __restrict__ psiyr_all, float* __restrict__ psiyw_all,
    const float* __restrict__ psixr_all, float* __restrict__ psixw_all,
    float* __restrict__ zetay_all, float* __restrict__ zetax_all,
    const float* __restrict__ v2dt2, const float* __restrict__ prof,
    const unsigned* __restrict__ srcmask,
    const unsigned long long* __restrict__ recmask,
    const float* __restrict__ amps, float* __restrict__ out, int t) {
    int x = blockIdx.x * 64 + threadIdx.x;
    int y = blockIdx.y * 4 + threadIdx.y;
    int shot = blockIdx.z;
    if (x >= NXP_ || y >= NYP_) return;
    const long f = (long)LST * LST;
    const float* wfc   = wfc_all   + shot * f;
    float*       wfn   = wfn_all   + shot * f;
    const float* psiyr = psiyr_all + shot * f;
    float*       psiyw = psiyw_all + shot * f;
    const float* psixr = psixr_all + shot * f;
    float*       psixw = psixw_all + shot * f;
    float*       zetay = zetay_all + shot * f;
    float*       zetax = zetax_all + shot * f;
    const int c = (y + LGD) * LST + (x + LGD);
    float wy[9], wx[9];
#pragma unroll
    for (int k = 0; k < 9; k++) wy[k] = wfc[c + (k - 4) * LST];
#pragma unroll
    for (int k = 0; k < 9; k++) wx[k] = (k == 4) ? wy[4] : wfc[c + (k - 4)];
    const float ih = 0.2f, ih2 = 0.04f;
    const float C1A = 2.0f / 3.0f, C1B = 1.0f / 12.0f;
    const float C2A = 4.0f / 3.0f, C2B = -1.0f / 12.0f, C2C = -2.5f;
    float d2y = (C2B * (wy[2] + wy[6]) + C2A * (wy[3] + wy[5]) + C2C * wy[4]) * ih2;
    float d2x = (C2B * (wx[2] + wx[6]) + C2A * (wx[3] + wx[5]) + C2C * wx[4]) * ih2;
    float dwdy[5], dwdx[5];
#pragma unroll
    for (int j = 0; j < 5; j++) {
        dwdy[j] = (C1A * (wy[j + 3] - wy[j + 1]) - C1B * (wy[j + 4] - wy[j])) * ih;
        dwdx[j] = (C1A * (wx[j + 3] - wx[j + 1]) - C1B * (wx[j + 4] - wx[j])) * ih;
    }
    float pny[5], pnx[5];
#pragma unroll
    for (int j = 0; j < 5; j++) {
        int yy = y + j - 2;
        pny[j] = prof[LST + LGD + yy] * psiyr[c + (j - 2) * LST] + prof[LGD + yy] * dwdy[j];
        int xx = x + j - 2;
        pnx[j] = prof[LST + LGD + xx] * psixr[c + (j - 2)] + prof[LGD + xx] * dwdx[j];
    }
    float dpsiy = (C1A * (pny[3] - pny[1]) - C1B * (pny[4] - pny[0])) * ih;
    float dpsix = (C1A * (pnx[3] - pnx[1]) - C1B * (pnx[4] - pnx[0])) * ih;
    float ay_ = prof[LGD + y], by_ = prof[LST + LGD + y];
    float ax_ = prof[LGD + x], bx_ = prof[LST + LGD + x];
    float zy = by_ * zetay[c] + ay_ * (d2y + dpsiy);
    float zx = bx_ * zetax[c] + ax_ * (d2x + dpsix);
    float lap = d2y + d2x + dpsiy + dpsix + zy + zx;
    float vd  = v2dt2[(y + LGD) * LST + (x + LGD)];
    float wfp = 2.0f * wy[4] - wfn[c] + vd * lap;
    unsigned sm = srcmask[shot * f + c];
    if (sm) {
#pragma unroll
        for (int s = 0; s < NSRC_; s++)
            if (sm & (1u << s)) wfp += vd * amps[(shot * NSRC_ + s) * NTT + t];
    }
    wfn[c]   = wfp;
    psiyw[c] = pny[2];
    psixw[c] = pnx[2];
    zetay[c] = zy;
    zetax[c] = zx;
    unsigned long long rm = recmask[shot * f + c];
    while (rm) {
        int r = __ffsll(rm) - 1;
        out[(shot * NREC_ + r) * NTT + t] = wfp;
        rm &= rm - 1;
    }
}

// ---------------- host ----------------
extern "C" void kernel_launch(void* const* d_in, const int* in_sizes, int n_in,
                              void* d_out, int out_size, void* d_ws, size_t ws_size,
                              hipStream_t stream) {
    const float* v      = (const float*)d_in[0];
    const float* amps   = (const float*)d_in[1];
    const int*   srcloc = (const int*)d_in[2];
    const int*   recloc = (const int*)d_in[3];
    float* out = (float*)d_out;
    float* base = (float*)d_ws;

    const long nbins = NSHOT_ * NTILE * NTILE;
    const long fused_words = 25L * FG + 2 * STG + 2 * nbins;   // 12 field arrays*2shots + v2 + prof + bins
    const bool use_fused = ws_size >= (size_t)(fused_words * 4);

    if (use_fused) {
        float* W0  = base;            // each: 2 shots * FG
        float* W1  = W0  + 2 * FG;
        float* W2  = W1  + 2 * FG;
        float* W3  = W2  + 2 * FG;
        float* PY0 = W3  + 2 * FG;
        float* PY1 = PY0 + 2 * FG;
        float* PX0 = PY1 + 2 * FG;
        float* PX1 = PX0 + 2 * FG;
        float* ZY0 = PX1 + 2 * FG;
        float* ZY1 = ZY0 + 2 * FG;
        float* ZX0 = ZY1 + 2 * FG;
        float* ZX1 = ZX0 + 2 * FG;
        float* v2  = ZX1 + 2 * FG;    // FG (shot-independent)
        float* prof = v2 + FG;        // 2*STG
        unsigned long long* recbin = (unsigned long long*)(prof + 2 * STG);

        zero_kernel<<<2048, 256, 0, stream>>>(base, fused_words);
        populateT_kernel<<<(NYP_ * NXP_ + 255) / 256, 256, 0, stream>>>(
            v, recloc, v2, prof, recbin);

        dim3 blk(256, 1, 1);
        dim3 grd(NTILE, NTILE, NSHOT_);
        // 62 launches of T=4 (t=0..247), then one T=2 (t=248..249)
        for (int j = 0; j < 63; j++) {
            const bool o = (j & 1);
            const float* rm = o ? W2 : W0;   // wf(t-1)
            const float* rc = o ? W3 : W1;   // wf(t)
            float* wA = o ? W0 : W2;         // wf(t+T-1)
            float* wB = o ? W1 : W3;         // wf(t+T)
            const float* py = o ? PY1 : PY0;  float* pyw = o ? PY0 : PY1;
            const float* px = o ? PX1 : PX0;  float* pxw = o ? PX0 : PX1;
            const float* zy = o ? ZY1 : ZY0;  float* zyw = o ? ZY0 : ZY1;
            const float* zx = o ? ZX1 : ZX0;  float* zxw = o ? ZX0 : ZX1;
            if (j < 62) {
                fusedT_kernel<4><<<grd, blk, 0, stream>>>(
                    rm, rc, wA, wB, py, pyw, px, pxw, zy, zyw, zx, zxw,
                    v2, prof, recbin, srcloc, recloc, amps, out, 4 * j);
            } else {
                fusedT_kernel<2><<<grd, blk, 0, stream>>>(
                    rm, rc, wA, wB, py, pyw, px, pxw, zy, zyw, zx, zxw,
                    v2, prof, recbin, srcloc, recloc, amps, out, 248);
            }
        }
    } else {
        // legacy round-0 path
        const long f = (long)LST * LST;
        float* wf0   = base;
        float* wf1   = wf0   + 2 * f;
        float* psiy0 = wf1   + 2 * f;
        float* psiy1 = psiy0 + 2 * f;
        float* psix0 = psiy1 + 2 * f;
        float* psix1 = psix0 + 2 * f;
        float* zetay = psix1 + 2 * f;
        float* zetax = zetay + 2 * f;
        float* v2dt2 = zetax + 2 * f;
        float* prof  = v2dt2 + f;
        unsigned* srcmask = (unsigned*)(prof + 2 * LST);
        unsigned long long* recmask = (unsigned long long*)(srcmask + 2 * f);
        const long total_words = 23 * f + 2 * LST;
        zero_kernel<<<4096, 256, 0, stream>>>(base, total_words);
        populateL_kernel<<<(NYP_ * NXP_ + 255) / 256, 256, 0, stream>>>(
            v, srcloc, recloc, v2dt2, prof, srcmask, recmask);
        dim3 blk(64, 4, 1);
        dim3 grd((NXP_ + 63) / 64, (NYP_ + 3) / 4, NSHOT_);
        for (int t = 0; t < NTT; t++) {
            const float* wc  = (t & 1) ? wf1 : wf0;
            float*       wn  = (t & 1) ? wf0 : wf1;
            const float* pyr = (t & 1) ? psiy1 : psiy0;
            float*       pyw = (t & 1) ? psiy0 : psiy1;
            const float* pxr = (t & 1) ? psix1 : psix0;
            float*       pxw = (t & 1) ? psix0 : psix1;
            stepL_kernel<<<grd, blk, 0, stream>>>(wc, wn, pyr, pyw, pxr, pxw,
                                                  zetay, zetax, v2dt2, prof,
                                                  srcmask, recmask, amps, out, t);
        }
    }
}

// Round 5
// 1273.349 us; speedup vs baseline: 2.9771x; 2.9771x over previous
//
#include <hip/hip_runtime.h>
#include <cstdint>

// ---------------- problem constants ----------------
#define NYD   256
#define NXD   256
#define PADC  22            // PML + FD_PAD
#define NYP_  300           // NY + 2*PAD
#define NXP_  300
#define NTT   250
#define NSHOT_ 2
#define NSRC_  8
#define NREC_  64
#define DT_   0.0005f

// guarded-array geometry: guard 28 covers tile overhang (cols 300..319) + stencil halo
#define GDN   28
#define STP   356           // NXP_ + 2*GDN
#define FP    (STP*STP)     // per-shot field words (126736)

// tile geometry: 64x4 output tile, 256 threads, 1 cell/thread
#define NTX   5             // ceil(300/64)
#define NTY   75            // 300/4
#define TPS   375           // tiles per shot
#define NWG   750           // total blocks

// ---------------- zero workspace ----------------
__global__ void zero_kernel(float* __restrict__ p, long n) {
    long i = (long)blockIdx.x * blockDim.x + threadIdx.x;
    long stride = (long)gridDim.x * blockDim.x;
    for (; i < n; i += stride) p[i] = 0.0f;
}

// ---------------- setup: v2dt2, PML profiles, src/rec tile bins ----------------
__global__ void populate_kernel(const float* __restrict__ v,
                                const int* __restrict__ srcloc,
                                const int* __restrict__ recloc,
                                float* __restrict__ v2dt2,   // [FP], guard stays 0
                                float* __restrict__ prof,    // [2*STP]: a, b (guard 0)
                                unsigned* __restrict__ srcbin,            // [2][TPS]
                                unsigned long long* __restrict__ recbin) { // [2][TPS]
    int i = blockIdx.x * 256 + threadIdx.x;

    if (i < NYP_ * NXP_) {
        int y = i / NXP_, x = i % NXP_;
        int vy = min(max(y - PADC, 0), NYD - 1);
        int vx = min(max(x - PADC, 0), NXD - 1);
        float vv = v[vy * NXD + vx];
        v2dt2[(y + GDN) * STP + (x + GDN)] = vv * vv * (DT_ * DT_);
    }

    if (i < NYP_) {  // DY == DX and NYP == NXP: one profile pair serves both axes
        float fi = (float)i;
        float d = fmaxf(22.0f - fi, fi - 277.0f);
        float frac = fminf(fmaxf(d * (1.0f / 20.0f), 0.0f), 1.0f);
        float sigma_max = 3.0f * 4000.0f * logf(1000.0f) / (2.0f * 20.0f * 5.0f);
        float sigma = sigma_max * frac * frac;
        float alpha = 3.14159265358979323846f * 25.0f * (1.0f - frac);
        float b = expf(-(sigma + alpha) * DT_);
        float a = sigma / (sigma + alpha + 1e-9f) * (b - 1.0f);
        prof[GDN + i] = a;
        prof[STP + GDN + i] = b;
    }

    if (i < NSHOT_ * NSRC_) {
        int sy = srcloc[2 * i] + PADC;
        int sx = srcloc[2 * i + 1] + PADC;
        int shot = i / NSRC_;
        int tl = (sy / 4) * NTX + (sx / 64);
        atomicOr(&srcbin[shot * TPS + tl], 1u << (i % NSRC_));
    }

    if (i >= 1024 && i < 1024 + NSHOT_ * NREC_) {
        int j = i - 1024;
        int ry = recloc[2 * j] + PADC;
        int rx = recloc[2 * j + 1] + PADC;
        int shot = j / NREC_;
        int tl = (ry / 4) * NTX + (rx / 64);
        atomicOr(&recbin[shot * TPS + tl], 1ull << (j % NREC_));
    }
}

// ---------------- one time step, LDS-staged ----------------
// 64x4 tile per 256-thread block. Stage wf/psi tiles via float4 into LDS
// (independent loads -> one latency exposure), stencil reads from LDS
// (64-consecutive per wave -> bank-conflict-free). zeta/wfm/v2 are self-cell
// scalar coalesced loads. Per-cell src/rec masks replaced by tile bins.
// Guard ring GDN=28 (always zero, prof/v2 zero there) makes every staged
// access in-bounds and keeps Dirichlet boundaries exact; overhang cells
// (x>=300) compute and store zeros into the guard harmlessly.
// Bijective XCD swizzle (q=93, r=6) gives each XCD a contiguous y-band so
// y-halo re-reads hit the local L2.
__global__ __launch_bounds__(256) void step_kernel(
    const float* __restrict__ wfc_g,   // wf(t)   [2][FP]
    float* __restrict__ wfn_g,         // wf(t-1) in / wf(t+1) out
    const float* __restrict__ pyr_g, float* __restrict__ pyw_g,
    const float* __restrict__ pxr_g, float* __restrict__ pxw_g,
    float* __restrict__ zy_g, float* __restrict__ zx_g,
    const float* __restrict__ v2_g, const float* __restrict__ prof,
    const unsigned* __restrict__ srcbin,
    const unsigned long long* __restrict__ recbin,
    const int* __restrict__ srcloc, const int* __restrict__ recloc,
    const float* __restrict__ amps,   // [NSHOT][NSRC][NT]
    float* __restrict__ out,          // [NSHOT][NREC][NT]
    int t) {
    // bijective XCD swizzle: NWG=750, 8 XCDs, q=93, r=6
    int orig = blockIdx.x;
    int xcd = orig & 7, idx = orig >> 3;
    int wgid = (xcd < 6) ? xcd * 94 + idx : 6 * 94 + (xcd - 6) * 93 + idx;
    int shot = wgid / TPS;
    int tl   = wgid - shot * TPS;
    int ty0  = (tl / NTX) * 4;
    int tx0  = (tl % NTX) * 64;

    const float* wfc = wfc_g + shot * FP;
    float*       wfn = wfn_g + shot * FP;
    const float* pyr = pyr_g + shot * FP;
    float*       pyw = pyw_g + shot * FP;
    const float* pxr = pxr_g + shot * FP;
    float*       pxw = pxw_g + shot * FP;
    float*       zyg = zy_g  + shot * FP;
    float*       zxg = zx_g  + shot * FP;

    __shared__ float swf[12][72];    // wf(t): rows ty0-4..ty0+7, cols tx0-4..tx0+67
    __shared__ float spy[8][64];     // psiy:  rows ty0-2..ty0+5, cols tx0..tx0+63
    __shared__ float spx[4][72];     // psix:  rows ty0..ty0+3,  cols tx0-4..tx0+67
    __shared__ float sya[8], syb[8], sxa[68], sxb[68];
    __shared__ int   ssy[NSRC_], ssx[NSRC_], sry[NREC_], srx[NREC_];
    __shared__ unsigned sbs;
    __shared__ unsigned long long sbr;

    const int tid = threadIdx.x;
    const int lx = tid & 63, ly = tid >> 6;
    const int y = ty0 + ly, x = tx0 + lx;
    const int g = (y + GDN) * STP + (x + GDN);

    // self-cell state (independent scalar loads, coalesced)
    float wm = wfn[g];
    float zy = zyg[g];
    float zx = zxg[g];
    float vd = v2_g[g];

    // staged loads (float4, all independent)
    if (tid < 216) {                              // wf: 12 x 18 float4
        int rr = tid / 18, cc = tid % 18;
        const float4 val = *(reinterpret_cast<const float4*>(
            wfc + (ty0 - 4 + rr + GDN) * STP + (tx0 - 4 + GDN)) + cc);
        *reinterpret_cast<float4*>(&swf[rr][cc * 4]) = val;
    }
    if (tid < 128) {                              // psiy: 8 x 16 float4
        int rr = tid / 16, cc = tid % 16;
        const float4 val = *(reinterpret_cast<const float4*>(
            pyr + (ty0 - 2 + rr + GDN) * STP + (tx0 + GDN)) + cc);
        *reinterpret_cast<float4*>(&spy[rr][cc * 4]) = val;
    }
    if (tid < 72) {                               // psix: 4 x 18 float4
        int rr = tid / 18, cc = tid % 18;
        const float4 val = *(reinterpret_cast<const float4*>(
            pxr + (ty0 + rr + GDN) * STP + (tx0 - 4 + GDN)) + cc);
        *reinterpret_cast<float4*>(&spx[rr][cc * 4]) = val;
    }
    if (tid < 8) {
        sya[tid] = prof[GDN + ty0 - 2 + tid];
        syb[tid] = prof[STP + GDN + ty0 - 2 + tid];
        ssy[tid] = srcloc[(shot * NSRC_ + tid) * 2]     + PADC;
        ssx[tid] = srcloc[(shot * NSRC_ + tid) * 2 + 1] + PADC;
    }
    if (tid < 68) {
        sxa[tid] = prof[GDN + tx0 - 2 + tid];
        sxb[tid] = prof[STP + GDN + tx0 - 2 + tid];
    }
    if (tid < NREC_) {
        sry[tid] = recloc[(shot * NREC_ + tid) * 2]     + PADC;
        srx[tid] = recloc[(shot * NREC_ + tid) * 2 + 1] + PADC;
    }
    if (tid == 0) {
        sbs = srcbin[shot * TPS + tl];
        sbr = recbin[shot * TPS + tl];
    }
    __syncthreads();

    const float ih  = 0.2f;    // 1/DY
    const float ih2 = 0.04f;   // 1/DY^2
    const float C1A = 2.0f / 3.0f, C1B = 1.0f / 12.0f;
    const float C2A = 4.0f / 3.0f, C2B = -1.0f / 12.0f, C2C = -2.5f;

    float wy[9];
#pragma unroll
    for (int k = 0; k < 9; k++) wy[k] = swf[ly + k][lx + 4];
    float wx[9];
#pragma unroll
    for (int k = 0; k < 9; k++) wx[k] = (k == 4) ? wy[4] : swf[ly + 4][lx + k];

    float d2y = (C2B * (wy[2] + wy[6]) + C2A * (wy[3] + wy[5]) + C2C * wy[4]) * ih2;
    float d2x = (C2B * (wx[2] + wx[6]) + C2A * (wx[3] + wx[5]) + C2C * wx[4]) * ih2;

    float pny[5], pnx[5];
#pragma unroll
    for (int j = 0; j < 5; j++) {
        float dwdy = (C1A * (wy[j + 3] - wy[j + 1]) - C1B * (wy[j + 4] - wy[j])) * ih;
        pny[j] = syb[ly + j] * spy[ly + j][lx] + sya[ly + j] * dwdy;
        float dwdx = (C1A * (wx[j + 3] - wx[j + 1]) - C1B * (wx[j + 4] - wx[j])) * ih;
        pnx[j] = sxb[lx + j] * spx[ly][lx + j + 2] + sxa[lx + j] * dwdx;
    }

    float dpsiy = (C1A * (pny[3] - pny[1]) - C1B * (pny[4] - pny[0])) * ih;
    float dpsix = (C1A * (pnx[3] - pnx[1]) - C1B * (pnx[4] - pnx[0])) * ih;

    float ay_ = sya[ly + 2], by_ = syb[ly + 2];
    float ax_ = sxa[lx + 2], bx_ = sxb[lx + 2];

    zy = by_ * zy + ay_ * (d2y + dpsiy);
    zx = bx_ * zx + ax_ * (d2x + dpsix);

    float lap = d2y + d2x + dpsiy + dpsix + zy + zx;
    float wfp = 2.0f * wy[4] - wm + vd * lap;

    // source injection (matches reference order: before store & record)
    if (sbs) {
#pragma unroll
        for (int q = 0; q < NSRC_; q++)
            if ((sbs & (1u << q)) && ssy[q] == y && ssx[q] == x)
                wfp += vd * amps[(shot * NSRC_ + q) * NTT + t];
    }

    wfn[g] = wfp;
    pyw[g] = pny[2];
    pxw[g] = pnx[2];
    zyg[g] = zy;
    zxg[g] = zx;

    unsigned long long rb = sbr;
    while (rb) {
        int r = __ffsll(rb) - 1;
        rb &= rb - 1;
        if (sry[r] == y && srx[r] == x)
            out[(shot * NREC_ + r) * NTT + t] = wfp;
    }
}

// ---------------- host ----------------
extern "C" void kernel_launch(void* const* d_in, const int* in_sizes, int n_in,
                              void* d_out, int out_size, void* d_ws, size_t ws_size,
                              hipStream_t stream) {
    const float* v      = (const float*)d_in[0];
    const float* amps   = (const float*)d_in[1];
    const int*   srcloc = (const int*)d_in[2];
    const int*   recloc = (const int*)d_in[3];
    float* out = (float*)d_out;

    float* base = (float*)d_ws;
    float* WF0 = base;             // each: [2 shots][FP]
    float* WF1 = WF0 + 2L * FP;
    float* PY0 = WF1 + 2L * FP;
    float* PY1 = PY0 + 2L * FP;
    float* PX0 = PY1 + 2L * FP;
    float* PX1 = PX0 + 2L * FP;
    float* ZY  = PX1 + 2L * FP;    // in-place (self-cell)
    float* ZX  = ZY  + 2L * FP;
    float* V2  = ZX  + 2L * FP;    // [FP], shot-independent
    float* PROF = V2 + FP;         // [2*STP]
    unsigned* SRCBIN = (unsigned*)(PROF + 2 * STP);                 // 750 words
    unsigned long long* RECBIN = (unsigned long long*)(SRCBIN + NSHOT_ * TPS);  // 1500 words

    const long total_words = 17L * FP + 2 * STP + NSHOT_ * TPS + 2L * NSHOT_ * TPS;

    zero_kernel<<<2048, 256, 0, stream>>>(base, total_words);
    populate_kernel<<<(NYP_ * NXP_ + 255) / 256, 256, 0, stream>>>(
        v, srcloc, recloc, V2, PROF, SRCBIN, RECBIN);

    for (int t = 0; t < NTT; t++) {
        const bool o = (t & 1);
        step_kernel<<<NWG, 256, 0, stream>>>(
            o ? WF1 : WF0, o ? WF0 : WF1,
            o ? PY1 : PY0, o ? PY0 : PY1,
            o ? PX1 : PX0, o ? PX0 : PX1,
            ZY, ZX, V2, PROF, SRCBIN, RECBIN,
            srcloc, recloc, amps, out, t);
    }
}